// Round 1
// baseline (122966.528 us; speedup 1.0000x reference)
//
#include <hip/hip_runtime.h>
#include <hip/hip_bf16.h>
#include <hip/hip_cooperative_groups.h>

namespace cg = cooperative_groups;

// Problem constants
constexpr int B_N = 64;
constexpr int T_N = 1024;
constexpr int H_N = 512;
constexpr long long BT_N = (long long)B_N * T_N;   // 65536

// ---------------------------------------------------------------------------
// SGEMM: C[M,N] = act(A[M,K] @ W[N,K]^T + bias[N]);  A,W fp32 row-major.
// 128x128 C-tile, BK=16, 256 threads, 8x8 micro-tile per thread.
// ---------------------------------------------------------------------------
__device__ inline void store_val(float* p, float v) { *p = v; }
__device__ inline void store_val(__hip_bfloat16* p, float v) { *p = __float2bfloat16(v); }

template <typename OutT, bool RELU>
__global__ __launch_bounds__(256)
void sgemm_kernel(const float* __restrict__ A, const float* __restrict__ W,
                  const float* __restrict__ bias, OutT* __restrict__ C,
                  int M, int N, int K)
{
    __shared__ float As[16][132];   // [k][m], padded
    __shared__ float Ws[16][132];   // [k][n], padded

    const int tid = threadIdx.x;
    const int bm  = blockIdx.y;
    const int bn  = blockIdx.x;

    // loader mapping: 2 lanes per row, 8 k-floats each (two float4)
    const int lr = tid >> 1;          // 0..127 tile row
    const int lk = (tid & 1) * 8;     // 0 or 8
    // compute mapping
    const int ty = tid >> 4;          // 0..15
    const int tx = tid & 15;          // 0..15

    const float* Ap = A + (size_t)(bm * 128 + lr) * K + lk;
    const float* Wp = W + (size_t)(bn * 128 + lr) * K + lk;

    float acc[8][8];
#pragma unroll
    for (int i = 0; i < 8; ++i)
#pragma unroll
        for (int j = 0; j < 8; ++j) acc[i][j] = 0.f;

    for (int k0 = 0; k0 < K; k0 += 16) {
        float4 a0 = *(const float4*)(Ap + k0);
        float4 a1 = *(const float4*)(Ap + k0 + 4);
        float4 w0 = *(const float4*)(Wp + k0);
        float4 w1 = *(const float4*)(Wp + k0 + 4);
        __syncthreads();  // protect previous iteration's LDS reads
        As[lk + 0][lr] = a0.x; As[lk + 1][lr] = a0.y; As[lk + 2][lr] = a0.z; As[lk + 3][lr] = a0.w;
        As[lk + 4][lr] = a1.x; As[lk + 5][lr] = a1.y; As[lk + 6][lr] = a1.z; As[lk + 7][lr] = a1.w;
        Ws[lk + 0][lr] = w0.x; Ws[lk + 1][lr] = w0.y; Ws[lk + 2][lr] = w0.z; Ws[lk + 3][lr] = w0.w;
        Ws[lk + 4][lr] = w1.x; Ws[lk + 5][lr] = w1.y; Ws[lk + 6][lr] = w1.z; Ws[lk + 7][lr] = w1.w;
        __syncthreads();
#pragma unroll
        for (int k = 0; k < 16; ++k) {
            float a[8], w[8];
            *(float4*)&a[0] = *(const float4*)&As[k][ty * 8];
            *(float4*)&a[4] = *(const float4*)&As[k][ty * 8 + 4];
            *(float4*)&w[0] = *(const float4*)&Ws[k][tx * 8];
            *(float4*)&w[4] = *(const float4*)&Ws[k][tx * 8 + 4];
#pragma unroll
            for (int i = 0; i < 8; ++i)
#pragma unroll
                for (int j = 0; j < 8; ++j)
                    acc[i][j] = fmaf(a[i], w[j], acc[i][j]);
        }
    }

    const int row0 = bm * 128 + ty * 8;
    const int col0 = bn * 128 + tx * 8;
    float bv[8];
#pragma unroll
    for (int j = 0; j < 8; ++j) bv[j] = bias[col0 + j];
#pragma unroll
    for (int i = 0; i < 8; ++i) {
#pragma unroll
        for (int j = 0; j < 8; ++j) {
            float v = acc[i][j] + bv[j];
            if (RELU) v = fmaxf(v, 0.f);
            store_val(C + (size_t)(row0 + i) * N + col0 + j, v);
        }
    }
}

// ---------------------------------------------------------------------------
// Cooperative GRU scan for one layer.
// gi [B,T,3H] bf16 (input-side pre-activations incl. b_ih), whh [3H,H] fp32,
// bhh [3H], y [B,T,H] fp32 output, h0/h1 [B,H] fp32 ping-pong hidden state.
// Grid: 128 blocks x 512 threads. Block owns JB=4 hidden columns.
// Thread = (k-half, batch-row, jj): 3 partial dots of 256, LDS-reduce pairs.
// ---------------------------------------------------------------------------
__global__ __launch_bounds__(512)
void gru_scan_kernel(const __hip_bfloat16* __restrict__ gi,
                     const float* __restrict__ whh,
                     const float* __restrict__ bhh,
                     float* __restrict__ y,
                     float* __restrict__ h0,
                     float* __restrict__ h1)
{
    constexpr int H = 512, JB = 4, T = 1024;
    __shared__ float wsh[3 * JB][H];  // 24 KB: rows = gate*4 + jj
    __shared__ float red[256][3];     // partial sums from half==1

    cg::grid_group grid = cg::this_grid();

    const int tid  = threadIdx.x;
    const int half = tid >> 8;        // 0/1 k-half
    const int rj   = tid & 255;
    const int r    = rj >> 2;         // batch row 0..63
    const int jj   = rj & 3;          // 0..3
    const int j0   = blockIdx.x * JB;
    const int j    = j0 + jj;

    // stage W_hh slice once (constant over time)
    for (int idx = tid; idx < 3 * JB * H; idx += 512) {
        int row  = idx >> 9;    // /512
        int k    = idx & 511;
        int gate = row >> 2;
        int rr   = row & 3;
        wsh[row][k] = whh[((size_t)gate * 512 + j0 + rr) * H + k];
    }
    const float b_r = bhh[j];
    const float b_z = bhh[512 + j];
    const float b_n = bhh[1024 + j];

    if (half == 0) h0[r * H + j] = 0.f;   // h(-1) = 0
    grid.sync();                          // also makes wsh + h0 visible

    const float* hc = h0;
    float* hn = h1;

    for (int t = 0; t < T; ++t) {
        // issue gi / h_prev loads early (half==0 only uses them)
        float ir = 0.f, iz = 0.f, in_ = 0.f, hprev = 0.f;
        if (half == 0) {
            const __hip_bfloat16* g = gi + ((size_t)r * T + t) * (3 * H);
            ir    = __bfloat162float(g[j]);
            iz    = __bfloat162float(g[512 + j]);
            in_   = __bfloat162float(g[1024 + j]);
            hprev = hc[r * H + j];
        }

        const float* hrow = hc + r * H + half * 256;
        const float* wr = &wsh[jj][half * 256];
        const float* wz = &wsh[4 + jj][half * 256];
        const float* wn = &wsh[8 + jj][half * 256];

        // 12 independent accumulator chains to avoid FMA latency serialization
        float s0 = 0.f, s1 = 0.f, s2 = 0.f, s3 = 0.f;
        float z0 = 0.f, z1 = 0.f, z2 = 0.f, z3 = 0.f;
        float n0 = 0.f, n1 = 0.f, n2 = 0.f, n3 = 0.f;
#pragma unroll 8
        for (int k = 0; k < 256; k += 4) {
            float4 hv = *(const float4*)(hrow + k);
            float4 v;
            v = *(const float4*)(wr + k);
            s0 = fmaf(hv.x, v.x, s0); s1 = fmaf(hv.y, v.y, s1);
            s2 = fmaf(hv.z, v.z, s2); s3 = fmaf(hv.w, v.w, s3);
            v = *(const float4*)(wz + k);
            z0 = fmaf(hv.x, v.x, z0); z1 = fmaf(hv.y, v.y, z1);
            z2 = fmaf(hv.z, v.z, z2); z3 = fmaf(hv.w, v.w, z3);
            v = *(const float4*)(wn + k);
            n0 = fmaf(hv.x, v.x, n0); n1 = fmaf(hv.y, v.y, n1);
            n2 = fmaf(hv.z, v.z, n2); n3 = fmaf(hv.w, v.w, n3);
        }
        float sr = (s0 + s1) + (s2 + s3);
        float sz = (z0 + z1) + (z2 + z3);
        float sn = (n0 + n1) + (n2 + n3);

        if (half == 1) { red[rj][0] = sr; red[rj][1] = sz; red[rj][2] = sn; }
        __syncthreads();
        if (half == 0) {
            sr += red[rj][0]; sz += red[rj][1]; sn += red[rj][2];
            float rg = 1.f / (1.f + __expf(-(ir + sr + b_r)));
            float zg = 1.f / (1.f + __expf(-(iz + sz + b_z)));
            float ng = tanhf(in_ + rg * (sn + b_n));
            float hv = (1.f - zg) * ng + zg * hprev;
            hn[r * H + j] = hv;
            y[((size_t)r * T + t) * H + j] = hv;
        }
        grid.sync();
        const float* tmp = hc; hc = hn; hn = (float*)tmp;
    }
}

// ---------------------------------------------------------------------------
// Host-side launch
// ---------------------------------------------------------------------------
extern "C" void kernel_launch(void* const* d_in, const int* in_sizes, int n_in,
                              void* d_out, int out_size, void* d_ws, size_t ws_size,
                              hipStream_t stream)
{
    const float* x    = (const float*)d_in[0];
    const float* w_in = (const float*)d_in[1];
    const float* b_in = (const float*)d_in[2];
    const float* w_ih = (const float*)d_in[3];
    const float* w_hh = (const float*)d_in[4];
    const float* b_ih = (const float*)d_in[5];
    const float* b_hh = (const float*)d_in[6];
    const float* w_o1 = (const float*)d_in[7];
    const float* b_o1 = (const float*)d_in[8];
    const float* w_o2 = (const float*)d_in[9];
    const float* b_o2 = (const float*)d_in[10];
    float* out = (float*)d_out;

    // workspace layout (total ~336 MB)
    char* ws = (char*)d_ws;
    const size_t GI_BYTES  = (size_t)BT_N * 1536 * sizeof(__hip_bfloat16); // 201326592
    const size_t ACT_BYTES = (size_t)BT_N * 512 * sizeof(float);           // 134217728
    __hip_bfloat16* gi = (__hip_bfloat16*)ws;
    float* act = (float*)(ws + GI_BYTES);
    float* h0  = (float*)(ws + GI_BYTES + ACT_BYTES);
    float* h1  = (float*)(ws + GI_BYTES + ACT_BYTES + 131072);
    float* tmp = (float*)ws;  // MLP intermediate reuses gi region after scans

    dim3 blk(256);
    const int M = (int)BT_N;

    // input linear + ReLU: [BT,512] = relu(x @ w_in^T + b_in)
    sgemm_kernel<float, true><<<dim3(4, 512), blk, 0, stream>>>(x, w_in, b_in, act, M, 512, 512);

    for (int l = 0; l < 4; ++l) {
        const float* wih_l = w_ih + (size_t)l * 1536 * 512;
        const float* whh_l = w_hh + (size_t)l * 1536 * 512;
        const float* bih_l = b_ih + (size_t)l * 1536;
        const float* bhh_l = b_hh + (size_t)l * 1536;

        // gi = act @ w_ih^T + b_ih  (stored bf16)
        sgemm_kernel<__hip_bfloat16, false><<<dim3(12, 512), blk, 0, stream>>>(
            act, wih_l, bih_l, gi, M, 1536, 512);

        // cooperative scan over T; writes layer output back into act
        void* args[] = { (void*)&gi, (void*)&whh_l, (void*)&bhh_l,
                         (void*)&act, (void*)&h0, (void*)&h1 };
        hipLaunchCooperativeKernel((void*)gru_scan_kernel, dim3(128), dim3(512),
                                   args, 0, stream);
    }

    // output MLP
    sgemm_kernel<float, true><<<dim3(4, 512), blk, 0, stream>>>(act, w_o1, b_o1, tmp, M, 512, 512);
    sgemm_kernel<float, false><<<dim3(4, 512), blk, 0, stream>>>(tmp, w_o2, b_o2, out, M, 512, 512);
}

// Round 2
// 90723.792 us; speedup vs baseline: 1.3554x; 1.3554x over previous
//
#include <hip/hip_runtime.h>
#include <hip/hip_bf16.h>
#include <hip/hip_cooperative_groups.h>

namespace cg = cooperative_groups;

typedef __attribute__((ext_vector_type(8))) __bf16 bf16x8;
typedef __attribute__((ext_vector_type(4))) float f32x4;

constexpr int B_N = 64;
constexpr int T_N = 1024;
constexpr int H_N = 512;
constexpr long long BT_N = (long long)B_N * T_N;   // 65536

// ---------------------------------------------------------------------------
// fp32 -> bf16 convert (4 elems/thread, grid-stride)
// ---------------------------------------------------------------------------
__global__ void cvt_f32_bf16(const float* __restrict__ src,
                             __hip_bfloat16* __restrict__ dst, long long n4)
{
    long long i = (long long)blockIdx.x * blockDim.x + threadIdx.x;
    long long stride = (long long)gridDim.x * blockDim.x;
    for (; i < n4; i += stride) {
        float4 v = ((const float4*)src)[i];
        __hip_bfloat16* d = dst + i * 4;
        d[0] = __float2bfloat16(v.x);
        d[1] = __float2bfloat16(v.y);
        d[2] = __float2bfloat16(v.z);
        d[3] = __float2bfloat16(v.w);
    }
}

// ---------------------------------------------------------------------------
// bf16 MFMA GEMM: C[M,N] = act(A[M,K] @ W[N,K]^T + bias)
// A,W bf16 row-major. 128x128 tile, BK=64, 256 thr (4 waves), wave = 64x64.
// ---------------------------------------------------------------------------
__device__ inline void store_val(float* p, float v) { *p = v; }
__device__ inline void store_val(__hip_bfloat16* p, float v) { *p = __float2bfloat16(v); }

template <typename OutT, bool RELU>
__global__ __launch_bounds__(256)
void mfma_gemm(const __hip_bfloat16* __restrict__ A,
               const __hip_bfloat16* __restrict__ W,
               const float* __restrict__ bias,
               OutT* __restrict__ C, int M, int N, int K)
{
    constexpr int LDT = 72;                 // padded LDS row stride (bf16 elems)
    __shared__ __hip_bfloat16 Asl[128 * LDT];
    __shared__ __hip_bfloat16 Bsl[128 * LDT];

    const int tid  = threadIdx.x;
    const int wv   = tid >> 6;
    const int lane = tid & 63;
    const int quad = lane >> 4;
    const int l16  = lane & 15;
    const int bm = blockIdx.y, bn = blockIdx.x;
    const int m0w = (wv & 1) * 64;
    const int n0w = (wv >> 1) * 64;

    f32x4 acc[4][4] = {};

    for (int k0 = 0; k0 < K; k0 += 64) {
        __syncthreads();   // protect previous iteration's LDS reads
#pragma unroll
        for (int i = 0; i < 4; ++i) {
            int c = tid + i * 256;          // 1024 chunks of 16B per tile
            int row = c >> 3, ch = c & 7;
            bf16x8 va = *(const bf16x8*)(A + (size_t)(bm * 128 + row) * K + k0 + ch * 8);
            bf16x8 vb = *(const bf16x8*)(W + (size_t)(bn * 128 + row) * K + k0 + ch * 8);
            *(bf16x8*)(Asl + row * LDT + ch * 8) = va;
            *(bf16x8*)(Bsl + row * LDT + ch * 8) = vb;
        }
        __syncthreads();
#pragma unroll
        for (int kc = 0; kc < 2; ++kc) {
            const int koff = kc * 32 + quad * 8;
            bf16x8 af[4], bfr[4];
#pragma unroll
            for (int mt = 0; mt < 4; ++mt)
                af[mt] = *(const bf16x8*)(Asl + (m0w + mt * 16 + l16) * LDT + koff);
#pragma unroll
            for (int nt = 0; nt < 4; ++nt)
                bfr[nt] = *(const bf16x8*)(Bsl + (n0w + nt * 16 + l16) * LDT + koff);
#pragma unroll
            for (int mt = 0; mt < 4; ++mt)
#pragma unroll
                for (int nt = 0; nt < 4; ++nt)
                    acc[mt][nt] = __builtin_amdgcn_mfma_f32_16x16x32_bf16(
                        af[mt], bfr[nt], acc[mt][nt], 0, 0, 0);
        }
    }

#pragma unroll
    for (int nt = 0; nt < 4; ++nt) {
        const int col = bn * 128 + n0w + nt * 16 + l16;
        const float bv = bias[col];
#pragma unroll
        for (int mt = 0; mt < 4; ++mt) {
#pragma unroll
            for (int rg = 0; rg < 4; ++rg) {
                const int row = bm * 128 + m0w + mt * 16 + quad * 4 + rg;
                float v = acc[mt][nt][rg] + bv;
                if (RELU) v = fmaxf(v, 0.f);
                store_val(C + (size_t)row * N + col, v);
            }
        }
    }
}

// ---------------------------------------------------------------------------
// Cooperative GRU scan, MFMA version. 16 blocks x 384 threads (6 waves).
// Wave w: gate g = w>>1, j-tile jt = w&1 -> W_hh rows [g*512 + j0 + jt*16, +16)
// B-fragments of W_hh live in VGPRs for all 1024 steps. A (=h_{t-1}, bf16)
// read straight from y at time t-1. Gate combine through padded LDS.
// y: [64][1024][512] bf16 — layer output AND hidden-state history.
// ---------------------------------------------------------------------------
__global__ __launch_bounds__(384)
void gru_scan_mfma(const __hip_bfloat16* __restrict__ gi,   // [64][1024][1536]
                   const __hip_bfloat16* __restrict__ whh,  // [1536][512] bf16
                   const float* __restrict__ bhh,           // [1536]
                   __hip_bfloat16* y)                       // [64][1024][512]
{
    cg::grid_group grid = cg::this_grid();
    __shared__ float gh[3][64][33];   // padded stride 33: conflict-free

    const int tid  = threadIdx.x;
    const int wv   = tid >> 6;        // 0..5
    const int lane = tid & 63;
    const int quad = lane >> 4;
    const int l16  = lane & 15;
    const int g    = wv >> 1;
    const int jt   = wv & 1;
    const int j0   = blockIdx.x * 32;
    const int colg = g * 512 + j0 + jt * 16;

    // W_hh fragments: constant across time, 64 VGPRs
    bf16x8 bfrag[16];
#pragma unroll
    for (int kc = 0; kc < 16; ++kc)
        bfrag[kc] = *(const bf16x8*)(whh + (size_t)(colg + l16) * 512 + kc * 32 + quad * 8);

    // per-lane A row offsets (element units), advance by t*512 each step
    size_t arow[4];
#pragma unroll
    for (int rt = 0; rt < 4; ++rt)
        arow[rt] = (size_t)(rt * 16 + l16) * 1024 * 512 + quad * 8;

    // combine-thread constants (threads 0..255): jj = tid & 31
    const int uj = tid & 31;
    const int um = tid >> 5;          // 0..7 (for tid<256)
    const float br  = bhh[j0 + uj];
    const float bz  = bhh[512 + j0 + uj];
    const float bn_ = bhh[1024 + j0 + uj];

    for (int t = 0; t < 1024; ++t) {
        // early gi preload for the combine phase (independent of MFMA)
        float pir[8], piz[8], pin[8];
        if (tid < 256) {
#pragma unroll
            for (int i = 0; i < 8; ++i) {
                const int m = i * 8 + um;
                const __hip_bfloat16* gp = gi + ((size_t)m * 1024 + t) * 1536 + j0 + uj;
                pir[i] = __bfloat162float(gp[0]);
                piz[i] = __bfloat162float(gp[512]);
                pin[i] = __bfloat162float(gp[1024]);
            }
        }

        f32x4 acc[4] = {};
        if (t > 0) {
            const __hip_bfloat16* yprev = y + (size_t)(t - 1) * 512;
#pragma unroll 1
            for (int kg = 0; kg < 4; ++kg) {    // bound VGPR pressure: 16 loads/group
#pragma unroll
                for (int rt = 0; rt < 4; ++rt) {
#pragma unroll
                    for (int k2 = 0; k2 < 4; ++k2) {
                        const int kc = kg * 4 + k2;
                        bf16x8 af = *(const bf16x8*)(yprev + arow[rt] + kc * 32);
                        acc[rt] = __builtin_amdgcn_mfma_f32_16x16x32_bf16(
                            af, bfrag[kc], acc[rt], 0, 0, 0);
                    }
                }
            }
        }

        // exchange: C/D layout col=l16 (j), row=quad*4+rg (m within 16-tile)
#pragma unroll
        for (int rt = 0; rt < 4; ++rt)
#pragma unroll
            for (int rg = 0; rg < 4; ++rg)
                gh[g][rt * 16 + quad * 4 + rg][jt * 16 + l16] = acc[rt][rg];
        __syncthreads();

        if (tid < 256) {
#pragma unroll
            for (int i = 0; i < 8; ++i) {
                const int m = i * 8 + um;
                const size_t yo = ((size_t)m * 1024 + t) * 512 + j0 + uj;
                float hprev = (t == 0) ? 0.f
                    : __bfloat162float(y[yo - 512]);
                float r = 1.f / (1.f + __expf(-(pir[i] + gh[0][m][uj] + br)));
                float z = 1.f / (1.f + __expf(-(piz[i] + gh[1][m][uj] + bz)));
                float n = tanhf(pin[i] + r * (gh[2][m][uj] + bn_));
                float hv = (1.f - z) * n + z * hprev;
                y[yo] = __float2bfloat16(hv);
            }
        }
        grid.sync();
    }
}

// ---------------------------------------------------------------------------
// Host-side launch
// ---------------------------------------------------------------------------
extern "C" void kernel_launch(void* const* d_in, const int* in_sizes, int n_in,
                              void* d_out, int out_size, void* d_ws, size_t ws_size,
                              hipStream_t stream)
{
    const float* x    = (const float*)d_in[0];
    const float* w_in = (const float*)d_in[1];
    const float* b_in = (const float*)d_in[2];
    const float* w_ih = (const float*)d_in[3];
    const float* w_hh = (const float*)d_in[4];
    const float* b_ih = (const float*)d_in[5];
    const float* b_hh = (const float*)d_in[6];
    const float* w_o1 = (const float*)d_in[7];
    const float* b_o1 = (const float*)d_in[8];
    const float* w_o2 = (const float*)d_in[9];
    const float* b_o2 = (const float*)d_in[10];
    float* out = (float*)d_out;

    // workspace layout (bytes), total ~270 MB
    char* ws = (char*)d_ws;
    const size_t GI_BYTES  = (size_t)BT_N * 1536 * 2;  // 201,326,592
    const size_t ACT_BYTES = (size_t)BT_N * 512 * 2;   //  67,108,864
    __hip_bfloat16* gi   = (__hip_bfloat16*)ws;                      // also hosts xbf & MLP tmp
    __hip_bfloat16* act  = (__hip_bfloat16*)(ws + GI_BYTES);
    __hip_bfloat16* wbf  = (__hip_bfloat16*)(ws + GI_BYTES + ACT_BYTES);
    __hip_bfloat16* xbf  = gi;                                        // alias: dead before gi written
    __hip_bfloat16* tmp  = gi;                                        // alias: MLP intermediate

    __hip_bfloat16* w_in_bf = wbf;                        // 262144
    __hip_bfloat16* w_ih_bf = wbf + 262144;               // 3,145,728
    __hip_bfloat16* w_hh_bf = w_ih_bf + 3145728;          // 3,145,728
    __hip_bfloat16* w_o1_bf = w_hh_bf + 3145728;          // 262144
    __hip_bfloat16* w_o2_bf = w_o1_bf + 262144;           // 262144

    // weight + input conversions
    cvt_f32_bf16<<<256, 256, 0, stream>>>(w_in, w_in_bf, 262144 / 4);
    cvt_f32_bf16<<<1024, 256, 0, stream>>>(w_ih, w_ih_bf, 3145728 / 4);
    cvt_f32_bf16<<<1024, 256, 0, stream>>>(w_hh, w_hh_bf, 3145728 / 4);
    cvt_f32_bf16<<<256, 256, 0, stream>>>(w_o1, w_o1_bf, 262144 / 4);
    cvt_f32_bf16<<<256, 256, 0, stream>>>(w_o2, w_o2_bf, 262144 / 4);
    cvt_f32_bf16<<<4096, 256, 0, stream>>>(x, xbf, BT_N * 512 / 4);

    const int M = (int)BT_N;

    // input linear + ReLU -> act (bf16)
    mfma_gemm<__hip_bfloat16, true><<<dim3(4, 512), 256, 0, stream>>>(
        xbf, w_in_bf, b_in, act, M, 512, 512);

    for (int l = 0; l < 4; ++l) {
        const __hip_bfloat16* wih_l = w_ih_bf + (size_t)l * 1536 * 512;
        const __hip_bfloat16* whh_l = w_hh_bf + (size_t)l * 1536 * 512;
        const float* bih_l = b_ih + (size_t)l * 1536;
        const float* bhh_l = b_hh + (size_t)l * 1536;

        // gi = act @ w_ih^T + b_ih  (bf16)
        mfma_gemm<__hip_bfloat16, false><<<dim3(12, 512), 256, 0, stream>>>(
            act, wih_l, bih_l, gi, M, 1536, 512);

        // cooperative scan; overwrites act with this layer's output
        __hip_bfloat16* yl = act;
        const __hip_bfloat16* gic = gi;
        void* args[] = { (void*)&gic, (void*)&whh_l, (void*)&bhh_l, (void*)&yl };
        hipLaunchCooperativeKernel((void*)gru_scan_mfma, dim3(16), dim3(384),
                                   args, 0, stream);
    }

    // output MLP: act -> tmp (relu, bf16) -> out (fp32)
    mfma_gemm<__hip_bfloat16, true><<<dim3(4, 512), 256, 0, stream>>>(
        act, w_o1_bf, b_o1, tmp, M, 512, 512);
    mfma_gemm<float, false><<<dim3(4, 512), 256, 0, stream>>>(
        tmp, w_o2_bf, b_o2, out, M, 512, 512);
}